// Round 1
// baseline (3331.245 us; speedup 1.0000x reference)
//
#include <hip/hip_runtime.h>
#include <hip/hip_bf16.h>
#include <math.h>

#define B_ 4
#define L_ 2048
#define D_ 1024
#define E_ 2048
#define N_ 16
#define DD_ 64
#define DCONV_ 4

static __device__ __forceinline__ float silu_f(float x) {
    return x / (1.f + __expf(-x));
}

// ---------------- RMSNorm: resid [B*L, D] -> xn ----------------
__global__ __launch_bounds__(256) void k_rmsnorm(const float* __restrict__ resid,
                                                 const float* __restrict__ nw,
                                                 float* __restrict__ out) {
    int row = blockIdx.x;
    const float* r = resid + (size_t)row * D_;
    int t = threadIdx.x;
    float4 v = *reinterpret_cast<const float4*>(&r[t * 4]);
    float ss = v.x * v.x + v.y * v.y + v.z * v.z + v.w * v.w;
#pragma unroll
    for (int o = 32; o >= 1; o >>= 1) ss += __shfl_xor(ss, o, 64);
    __shared__ float red[4];
    if ((t & 63) == 0) red[t >> 6] = ss;
    __syncthreads();
    float tot = red[0] + red[1] + red[2] + red[3];
    float rs = rsqrtf(tot * (1.f / (float)D_) + 1e-5f);
    float4 w4 = *reinterpret_cast<const float4*>(&nw[t * 4]);
    float4 o4;
    o4.x = v.x * rs * w4.x;
    o4.y = v.y * rs * w4.y;
    o4.z = v.z * rs * w4.z;
    o4.w = v.w * rs * w4.w;
    *reinterpret_cast<float4*>(&out[(size_t)row * D_ + t * 4]) = o4;
}

// ---------------- GEMM C[M,N] = A[M,K] @ W[N,K]^T  (+ epilogue) ----------------
// EPI: 0 = none, 1 = softplus(acc + bias[n]), 2 = acc + addsrc[m*N+n]
template <int EPI>
__global__ __launch_bounds__(256) void k_gemm_tn(const float* __restrict__ A,
                                                 const float* __restrict__ W,
                                                 const float* __restrict__ bias,
                                                 const float* __restrict__ addsrc,
                                                 float* __restrict__ C,
                                                 int M, int N, int K) {
    constexpr int BM = 64, BN = 64, BK = 32;
    constexpr int LDP = 68;  // padded row (floats), 272B = multiple of 16B
    __shared__ __align__(16) float As[BK][LDP];  // [k][m]
    __shared__ __align__(16) float Ws[BK][LDP];  // [k][n]
    int tid = threadIdx.x;
    int tx = tid & 15;
    int ty = tid >> 4;
    int m0 = blockIdx.y * BM;
    int n0 = blockIdx.x * BN;

    float acc[4][4];
#pragma unroll
    for (int i = 0; i < 4; ++i)
#pragma unroll
        for (int j = 0; j < 4; ++j) acc[i][j] = 0.f;

    for (int k0 = 0; k0 < K; k0 += BK) {
#pragma unroll
        for (int p = 0; p < 2; ++p) {
            int idx = tid + p * 256;     // float4 index 0..511
            int row = idx >> 3;          // 0..63
            int col4 = (idx & 7) * 4;    // 0..28
            float4 av = *reinterpret_cast<const float4*>(&A[(size_t)(m0 + row) * K + k0 + col4]);
            As[col4 + 0][row] = av.x;
            As[col4 + 1][row] = av.y;
            As[col4 + 2][row] = av.z;
            As[col4 + 3][row] = av.w;
            float4 wv = *reinterpret_cast<const float4*>(&W[(size_t)(n0 + row) * K + k0 + col4]);
            Ws[col4 + 0][row] = wv.x;
            Ws[col4 + 1][row] = wv.y;
            Ws[col4 + 2][row] = wv.z;
            Ws[col4 + 3][row] = wv.w;
        }
        __syncthreads();
#pragma unroll
        for (int kk = 0; kk < BK; ++kk) {
            float4 a4 = *reinterpret_cast<const float4*>(&As[kk][ty * 4]);
            float4 b4 = *reinterpret_cast<const float4*>(&Ws[kk][tx * 4]);
            float a[4] = {a4.x, a4.y, a4.z, a4.w};
            float b[4] = {b4.x, b4.y, b4.z, b4.w};
#pragma unroll
            for (int i = 0; i < 4; ++i)
#pragma unroll
                for (int j = 0; j < 4; ++j) acc[i][j] = fmaf(a[i], b[j], acc[i][j]);
        }
        __syncthreads();
    }

#pragma unroll
    for (int i = 0; i < 4; ++i) {
        int m = m0 + ty * 4 + i;
        int nbase = n0 + tx * 4;
        float4 o4;
        float vals[4];
#pragma unroll
        for (int j = 0; j < 4; ++j) {
            float v = acc[i][j];
            if (EPI == 1) {
                float z = v + bias[nbase + j];
                vals[j] = (z > 20.f) ? z : log1pf(expf(z));
            } else {
                vals[j] = v;
            }
        }
        if (EPI == 2) {
            float4 r4 = *reinterpret_cast<const float4*>(&addsrc[(size_t)m * N + nbase]);
            vals[0] += r4.x; vals[1] += r4.y; vals[2] += r4.z; vals[3] += r4.w;
        }
        o4.x = vals[0]; o4.y = vals[1]; o4.z = vals[2]; o4.w = vals[3];
        *reinterpret_cast<float4*>(&C[(size_t)m * N + nbase]) = o4;
    }
}

// ---------------- depthwise causal conv1d + bias + silu ----------------
__global__ __launch_bounds__(256) void k_conv_silu(const float* __restrict__ x,
                                                   const float* __restrict__ w,
                                                   const float* __restrict__ bias,
                                                   float* __restrict__ out) {
    int idx = blockIdx.x * 256 + threadIdx.x;  // [B,L,E] flat, e fastest
    int e = idx & (E_ - 1);
    int l = (idx / E_) & (L_ - 1);
    float4 wv = *reinterpret_cast<const float4*>(&w[e * 4]);
    float acc = bias[e];
    acc = fmaf(wv.w, x[idx], acc);
    if (l >= 1) acc = fmaf(wv.z, x[idx - E_], acc);
    if (l >= 2) acc = fmaf(wv.y, x[idx - 2 * E_], acc);
    if (l >= 3) acc = fmaf(wv.x, x[idx - 3 * E_], acc);
    out[idx] = silu_f(acc);
}

// ---------------- B/C projections: xs[M,E] @ {WB,WC}[16,E]^T ----------------
__global__ __launch_bounds__(256) void k_bc(const float* __restrict__ xs,
                                            const float* __restrict__ WB,
                                            const float* __restrict__ WC,
                                            float* __restrict__ Bm,
                                            float* __restrict__ Cm) {
    int tid = threadIdx.x;
    int n = tid & 31;   // 0..31 (B then C)
    int mi = tid >> 5;  // 0..7
    int m = blockIdx.x * 8 + mi;
    const float* xr = xs + (size_t)m * E_;
    const float* wr = (n < 16) ? (WB + (size_t)n * E_) : (WC + (size_t)(n - 16) * E_);
    float acc = 0.f;
    for (int k = 0; k < E_; k += 4) {
        float4 xv = *reinterpret_cast<const float4*>(&xr[k]);
        float4 wv = *reinterpret_cast<const float4*>(&wr[k]);
        acc = fmaf(xv.x, wv.x, acc);
        acc = fmaf(xv.y, wv.y, acc);
        acc = fmaf(xv.z, wv.z, acc);
        acc = fmaf(xv.w, wv.w, acc);
    }
    if (n < 16) Bm[(size_t)m * 16 + n] = acc;
    else        Cm[(size_t)m * 16 + (n - 16)] = acc;
}

// ---------------- selective scan, fused with W_D skip-add and silu(skip) gate ----------------
// One thread per (b,e) channel; h[16] in registers; writes yg over delta (elementwise safe).
__global__ __launch_bounds__(64) void k_scan(const float* __restrict__ xs,
                                             const float* __restrict__ delta,
                                             const float* __restrict__ Bm,
                                             const float* __restrict__ Cm,
                                             const float* __restrict__ A_log,
                                             const float* __restrict__ W_D,
                                             const float* __restrict__ skip,
                                             float* __restrict__ yg) {
    int idx = blockIdx.x * 64 + threadIdx.x;  // 0..B*E-1
    int e = idx & (E_ - 1);
    int b = idx / E_;
    float A[16];
#pragma unroll
    for (int n = 0; n < 16; n += 4) {
        float4 a4 = *reinterpret_cast<const float4*>(&A_log[e * 16 + n]);
        A[n + 0] = -__expf(a4.x);
        A[n + 1] = -__expf(a4.y);
        A[n + 2] = -__expf(a4.z);
        A[n + 3] = -__expf(a4.w);
    }
    float h[16];
#pragma unroll
    for (int n = 0; n < 16; ++n) h[n] = 0.f;
    float wd = W_D[e];
    size_t base = (size_t)b * L_ * E_ + e;
    size_t bc = (size_t)b * L_ * 16;
    for (int l = 0; l < L_; ++l) {
        float d = delta[base + (size_t)l * E_];
        float xv = xs[base + (size_t)l * E_];
        float sk = skip[base + (size_t)l * E_];
        float Bv[16], Cv[16];
#pragma unroll
        for (int n = 0; n < 16; n += 4) {
            float4 b4 = *reinterpret_cast<const float4*>(&Bm[bc + l * 16 + n]);
            Bv[n] = b4.x; Bv[n + 1] = b4.y; Bv[n + 2] = b4.z; Bv[n + 3] = b4.w;
            float4 c4 = *reinterpret_cast<const float4*>(&Cm[bc + l * 16 + n]);
            Cv[n] = c4.x; Cv[n + 1] = c4.y; Cv[n + 2] = c4.z; Cv[n + 3] = c4.w;
        }
        float dx = d * xv;
        float y = 0.f;
#pragma unroll
        for (int n = 0; n < 16; ++n) {
            h[n] = fmaf(__expf(d * A[n]), h[n], dx * Bv[n]);
            y = fmaf(h[n], Cv[n], y);
        }
        float g = silu_f(sk);
        yg[base + (size_t)l * E_] = (y + xv * wd) * g;
    }
}

extern "C" void kernel_launch(void* const* d_in, const int* in_sizes, int n_in,
                              void* d_out, int out_size, void* d_ws, size_t ws_size,
                              hipStream_t stream) {
    const float* resid  = (const float*)d_in[0];
    const float* norm_w = (const float*)d_in[1];
    const float* skip_w = (const float*)d_in[2];
    const float* in_w   = (const float*)d_in[3];
    const float* conv_w = (const float*)d_in[4];
    const float* conv_b = (const float*)d_in[5];
    const float* Wd1    = (const float*)d_in[6];
    const float* Wd2_w  = (const float*)d_in[7];
    const float* Wd2_b  = (const float*)d_in[8];
    const float* WB     = (const float*)d_in[9];
    const float* WC     = (const float*)d_in[10];
    const float* A_log  = (const float*)d_in[11];
    const float* W_D    = (const float*)d_in[12];
    const float* out_w  = (const float*)d_in[13];
    float* out = (float*)d_out;

    const int M = B_ * L_;                       // 8192
    float* ws = (float*)d_ws;
    float* xn    = ws;                           // [M, D]    8.4M floats
    float* skipb = xn + (size_t)M * D_;          // [M, E]   16.8M
    float* xin   = skipb + (size_t)M * E_;       // [M, E]   16.8M
    float* xs    = xin + (size_t)M * E_;         // [M, E]   16.8M
    // aliases (lifetimes disjoint / elementwise-safe):
    float* d1    = xn;                           // [M, DD]  (xn dead after in/skip GEMMs)
    float* Bm    = xn + (size_t)M * DD_;         // [M, 16]
    float* Cm    = Bm + (size_t)M * 16;          // [M, 16]
    float* delta = xin;                          // [M, E]   (xin dead after conv)
    float* yg    = delta;                        // scan writes same element it read

    dim3 blk(256);

    // 1. RMSNorm
    k_rmsnorm<<<dim3(M), blk, 0, stream>>>(resid, norm_w, xn);
    // 2. skip = xn @ skip_w^T   [M, E]
    k_gemm_tn<0><<<dim3(E_ / 64, M / 64), blk, 0, stream>>>(xn, skip_w, nullptr, nullptr, skipb, M, E_, D_);
    // 3. xin = xn @ in_w^T      [M, E]
    k_gemm_tn<0><<<dim3(E_ / 64, M / 64), blk, 0, stream>>>(xn, in_w, nullptr, nullptr, xin, M, E_, D_);
    // 4. xs = silu(causal depthwise conv(xin) + bias)
    k_conv_silu<<<dim3((M * E_) / 256), blk, 0, stream>>>(xin, conv_w, conv_b, xs);
    // 5. d1 = xs @ Wd1^T        [M, 64]
    k_gemm_tn<0><<<dim3(DD_ / 64, M / 64), blk, 0, stream>>>(xs, Wd1, nullptr, nullptr, d1, M, DD_, E_);
    // 6. delta = softplus(d1 @ Wd2^T + b)  [M, E]
    k_gemm_tn<1><<<dim3(E_ / 64, M / 64), blk, 0, stream>>>(d1, Wd2_w, Wd2_b, nullptr, delta, M, E_, DD_);
    // 7. Bm, Cm
    k_bc<<<dim3(M / 8), blk, 0, stream>>>(xs, WB, WC, Bm, Cm);
    // 8. scan (fused +x*W_D and *silu(skip)); yg overwrites delta elementwise
    k_scan<<<dim3((B_ * E_) / 64), dim3(64), 0, stream>>>(xs, delta, Bm, Cm, A_log, W_D, skipb, yg);
    // 9. out = resid + yg @ out_w^T
    k_gemm_tn<2><<<dim3(D_ / 64, M / 64), blk, 0, stream>>>(yg, out_w, nullptr, resid, out, M, D_, E_);
}

// Round 2
// 2318.889 us; speedup vs baseline: 1.4366x; 1.4366x over previous
//
#include <hip/hip_runtime.h>
#include <hip/hip_bf16.h>
#include <math.h>

#define B_ 4
#define L_ 2048
#define D_ 1024
#define E_ 2048
#define N_ 16
#define DD_ 64
#define DCONV_ 4

typedef __attribute__((ext_vector_type(8))) short bf16x8;
typedef __attribute__((ext_vector_type(4))) float f32x4;

static __device__ __forceinline__ float silu_f(float x) {
    return x / (1.f + __expf(-x));
}

static __device__ __forceinline__ ushort f2bf(float f) {
    __hip_bfloat16 h = __float2bfloat16(f);
    return *reinterpret_cast<ushort*>(&h);
}

// ---------------- RMSNorm: resid [B*L, D] -> xn (bf16) ----------------
__global__ __launch_bounds__(256) void k_rmsnorm_bf(const float* __restrict__ resid,
                                                    const float* __restrict__ nw,
                                                    ushort* __restrict__ out) {
    int row = blockIdx.x;
    const float* r = resid + (size_t)row * D_;
    int t = threadIdx.x;
    float4 v = *reinterpret_cast<const float4*>(&r[t * 4]);
    float ss = v.x * v.x + v.y * v.y + v.z * v.z + v.w * v.w;
#pragma unroll
    for (int o = 32; o >= 1; o >>= 1) ss += __shfl_xor(ss, o, 64);
    __shared__ float red[4];
    if ((t & 63) == 0) red[t >> 6] = ss;
    __syncthreads();
    float tot = red[0] + red[1] + red[2] + red[3];
    float rs = rsqrtf(tot * (1.f / (float)D_) + 1e-5f);
    float4 w4 = *reinterpret_cast<const float4*>(&nw[t * 4]);
    ushort4 o4;
    o4.x = f2bf(v.x * rs * w4.x);
    o4.y = f2bf(v.y * rs * w4.y);
    o4.z = f2bf(v.z * rs * w4.z);
    o4.w = f2bf(v.w * rs * w4.w);
    *reinterpret_cast<ushort4*>(&out[(size_t)row * D_ + t * 4]) = o4;
}

// ---------------- f32 -> bf16 cast (for weights) ----------------
__global__ __launch_bounds__(256) void k_cast_bf(const float* __restrict__ in,
                                                 ushort* __restrict__ out) {
    int i = blockIdx.x * 256 + threadIdx.x;  // float4 index
    float4 v = *reinterpret_cast<const float4*>(&in[i * 4]);
    ushort4 o;
    o.x = f2bf(v.x); o.y = f2bf(v.y); o.z = f2bf(v.z); o.w = f2bf(v.w);
    *reinterpret_cast<ushort4*>(&out[i * 4]) = o;
}

// ---------------- bf16 MFMA GEMM: C[M,N] = A[M,K] @ W[N,K]^T ----------------
// EPI: 0 = plain f32 store, 2 = += addsrc (residual) then f32 store
template <int EPI>
__global__ __launch_bounds__(256) void k_gemm_bf(const ushort* __restrict__ A,
                                                 const ushort* __restrict__ W,
                                                 const float* __restrict__ addsrc,
                                                 float* __restrict__ C,
                                                 int M, int N, int K) {
    constexpr int BM = 128, BN = 128, BK = 32, LDB = 40;  // 40 bf16 = 80B row stride
    __shared__ __align__(16) ushort As[BM * LDB];
    __shared__ __align__(16) ushort Ws[BN * LDB];
    int t = threadIdx.x;
    int m0 = blockIdx.y * BM, n0 = blockIdx.x * BN;
    int wave = t >> 6, lane = t & 63;
    int wr = wave >> 1, wc = wave & 1;     // wave quadrant (64x64)
    int lr = lane & 15, lg = lane >> 4;    // frag row/col, k-group

    f32x4 acc[4][4] = {};

    for (int k0 = 0; k0 < K; k0 += BK) {
#pragma unroll
        for (int p = 0; p < 2; ++p) {
            int f = t + p * 256;           // 16B chunk id, 0..511
            int row = f >> 2;              // 0..127
            int cg = (f & 3) * 8;          // bf16 col 0,8,16,24
            *reinterpret_cast<uint4*>(&As[row * LDB + cg]) =
                *reinterpret_cast<const uint4*>(&A[(size_t)(m0 + row) * K + k0 + cg]);
            *reinterpret_cast<uint4*>(&Ws[row * LDB + cg]) =
                *reinterpret_cast<const uint4*>(&W[(size_t)(n0 + row) * K + k0 + cg]);
        }
        __syncthreads();
        bf16x8 af[4], bfr[4];
#pragma unroll
        for (int i = 0; i < 4; ++i) {
            af[i]  = *reinterpret_cast<const bf16x8*>(&As[(wr * 64 + i * 16 + lr) * LDB + lg * 8]);
            bfr[i] = *reinterpret_cast<const bf16x8*>(&Ws[(wc * 64 + i * 16 + lr) * LDB + lg * 8]);
        }
#pragma unroll
        for (int i = 0; i < 4; ++i)
#pragma unroll
            for (int j = 0; j < 4; ++j)
                acc[i][j] = __builtin_amdgcn_mfma_f32_16x16x32_bf16(af[i], bfr[j], acc[i][j], 0, 0, 0);
        __syncthreads();
    }

#pragma unroll
    for (int i = 0; i < 4; ++i) {
        int mrow = m0 + wr * 64 + i * 16 + lg * 4;
#pragma unroll
        for (int j = 0; j < 4; ++j) {
            int ncol = n0 + wc * 64 + j * 16 + lr;
#pragma unroll
            for (int q = 0; q < 4; ++q) {
                float v = acc[i][j][q];
                size_t idx = (size_t)(mrow + q) * N + ncol;
                if (EPI == 2) v += addsrc[idx];
                C[idx] = v;
            }
        }
    }
}

// ---------------- f32 GEMM (small projections) ----------------
// EPI: 0 = none, 1 = softplus(acc + bias[n])
template <int EPI>
__global__ __launch_bounds__(256) void k_gemm_tn(const float* __restrict__ A,
                                                 const float* __restrict__ W,
                                                 const float* __restrict__ bias,
                                                 float* __restrict__ C,
                                                 int M, int N, int K) {
    constexpr int BM = 64, BN = 64, BK = 32;
    constexpr int LDP = 68;
    __shared__ __align__(16) float As[BK][LDP];
    __shared__ __align__(16) float Ws[BK][LDP];
    int tid = threadIdx.x;
    int tx = tid & 15;
    int ty = tid >> 4;
    int m0 = blockIdx.y * BM;
    int n0 = blockIdx.x * BN;

    float acc[4][4];
#pragma unroll
    for (int i = 0; i < 4; ++i)
#pragma unroll
        for (int j = 0; j < 4; ++j) acc[i][j] = 0.f;

    for (int k0 = 0; k0 < K; k0 += BK) {
#pragma unroll
        for (int p = 0; p < 2; ++p) {
            int idx = tid + p * 256;
            int row = idx >> 3;
            int col4 = (idx & 7) * 4;
            float4 av = *reinterpret_cast<const float4*>(&A[(size_t)(m0 + row) * K + k0 + col4]);
            As[col4 + 0][row] = av.x;
            As[col4 + 1][row] = av.y;
            As[col4 + 2][row] = av.z;
            As[col4 + 3][row] = av.w;
            float4 wv = *reinterpret_cast<const float4*>(&W[(size_t)(n0 + row) * K + k0 + col4]);
            Ws[col4 + 0][row] = wv.x;
            Ws[col4 + 1][row] = wv.y;
            Ws[col4 + 2][row] = wv.z;
            Ws[col4 + 3][row] = wv.w;
        }
        __syncthreads();
#pragma unroll
        for (int kk = 0; kk < BK; ++kk) {
            float4 a4 = *reinterpret_cast<const float4*>(&As[kk][ty * 4]);
            float4 b4 = *reinterpret_cast<const float4*>(&Ws[kk][tx * 4]);
            float a[4] = {a4.x, a4.y, a4.z, a4.w};
            float b[4] = {b4.x, b4.y, b4.z, b4.w};
#pragma unroll
            for (int i = 0; i < 4; ++i)
#pragma unroll
                for (int j = 0; j < 4; ++j) acc[i][j] = fmaf(a[i], b[j], acc[i][j]);
        }
        __syncthreads();
    }

#pragma unroll
    for (int i = 0; i < 4; ++i) {
        int m = m0 + ty * 4 + i;
        int nbase = n0 + tx * 4;
        float4 o4;
        float vals[4];
#pragma unroll
        for (int j = 0; j < 4; ++j) {
            float v = acc[i][j];
            if (EPI == 1) {
                float z = v + bias[nbase + j];
                vals[j] = (z > 20.f) ? z : log1pf(expf(z));
            } else {
                vals[j] = v;
            }
        }
        o4.x = vals[0]; o4.y = vals[1]; o4.z = vals[2]; o4.w = vals[3];
        *reinterpret_cast<float4*>(&C[(size_t)m * N + nbase]) = o4;
    }
}

// ---------------- depthwise causal conv1d + bias + silu ----------------
__global__ __launch_bounds__(256) void k_conv_silu(const float* __restrict__ x,
                                                   const float* __restrict__ w,
                                                   const float* __restrict__ bias,
                                                   float* __restrict__ out) {
    int idx = blockIdx.x * 256 + threadIdx.x;
    int e = idx & (E_ - 1);
    int l = (idx / E_) & (L_ - 1);
    float4 wv = *reinterpret_cast<const float4*>(&w[e * 4]);
    float acc = bias[e];
    acc = fmaf(wv.w, x[idx], acc);
    if (l >= 1) acc = fmaf(wv.z, x[idx - E_], acc);
    if (l >= 2) acc = fmaf(wv.y, x[idx - 2 * E_], acc);
    if (l >= 3) acc = fmaf(wv.x, x[idx - 3 * E_], acc);
    out[idx] = silu_f(acc);
}

// ---------------- B/C projections ----------------
__global__ __launch_bounds__(256) void k_bc(const float* __restrict__ xs,
                                            const float* __restrict__ WB,
                                            const float* __restrict__ WC,
                                            float* __restrict__ Bm,
                                            float* __restrict__ Cm) {
    int tid = threadIdx.x;
    int n = tid & 31;
    int mi = tid >> 5;
    int m = blockIdx.x * 8 + mi;
    const float* xr = xs + (size_t)m * E_;
    const float* wr = (n < 16) ? (WB + (size_t)n * E_) : (WC + (size_t)(n - 16) * E_);
    float acc = 0.f;
    for (int k = 0; k < E_; k += 4) {
        float4 xv = *reinterpret_cast<const float4*>(&xr[k]);
        float4 wv = *reinterpret_cast<const float4*>(&wr[k]);
        acc = fmaf(xv.x, wv.x, acc);
        acc = fmaf(xv.y, wv.y, acc);
        acc = fmaf(xv.z, wv.z, acc);
        acc = fmaf(xv.w, wv.w, acc);
    }
    if (n < 16) Bm[(size_t)m * 16 + n] = acc;
    else        Cm[(size_t)m * 16 + (n - 16)] = acc;
}

// ---------------- selective scan: 16 lanes per (b,e) channel ----------------
__global__ __launch_bounds__(256) void k_scan16(const float* __restrict__ xs,
                                                const float* __restrict__ delta,
                                                const float* __restrict__ Bm,
                                                const float* __restrict__ Cm,
                                                const float* __restrict__ A_log,
                                                const float* __restrict__ W_D,
                                                const float* __restrict__ skip,
                                                ushort* __restrict__ yg) {
    int t = threadIdx.x;
    int n = t & 15;
    int c = blockIdx.x * 16 + (t >> 4);    // channel 0..B*E-1
    int e = c & (E_ - 1);
    int b = c >> 11;
    float A = -__expf(A_log[e * 16 + n]);
    float h = 0.f;
    float wd = W_D[e];
    size_t base = (size_t)b * L_ * E_ + e;
    size_t bc = (size_t)b * L_ * 16 + n;
#pragma unroll 2
    for (int l = 0; l < L_; ++l) {
        float d  = delta[base + (size_t)l * E_];
        float xv = xs[base + (size_t)l * E_];
        float Bv = Bm[bc + (size_t)l * 16];
        float Cv = Cm[bc + (size_t)l * 16];
        h = fmaf(__expf(d * A), h, d * xv * Bv);
        float y = h * Cv;
        y += __shfl_xor(y, 1, 64);
        y += __shfl_xor(y, 2, 64);
        y += __shfl_xor(y, 4, 64);
        y += __shfl_xor(y, 8, 64);
        if (n == 0) {
            float sk = skip[base + (size_t)l * E_];
            float g = silu_f(sk);
            yg[base + (size_t)l * E_] = f2bf((y + xv * wd) * g);
        }
    }
}

extern "C" void kernel_launch(void* const* d_in, const int* in_sizes, int n_in,
                              void* d_out, int out_size, void* d_ws, size_t ws_size,
                              hipStream_t stream) {
    const float* resid  = (const float*)d_in[0];
    const float* norm_w = (const float*)d_in[1];
    const float* skip_w = (const float*)d_in[2];
    const float* in_w   = (const float*)d_in[3];
    const float* conv_w = (const float*)d_in[4];
    const float* conv_b = (const float*)d_in[5];
    const float* Wd1    = (const float*)d_in[6];
    const float* Wd2_w  = (const float*)d_in[7];
    const float* Wd2_b  = (const float*)d_in[8];
    const float* WB     = (const float*)d_in[9];
    const float* WC     = (const float*)d_in[10];
    const float* A_log  = (const float*)d_in[11];
    const float* W_D    = (const float*)d_in[12];
    const float* out_w  = (const float*)d_in[13];
    float* out = (float*)d_out;

    const int M = B_ * L_;                 // 8192
    char* p = (char*)d_ws;
    ushort* xn_bf   = (ushort*)p;  p += (size_t)M * D_ * 2;   // RMSNorm out (bf16)
    ushort* skw_bf  = (ushort*)p;  p += (size_t)E_ * D_ * 2;
    ushort* inw_bf  = (ushort*)p;  p += (size_t)E_ * D_ * 2;
    ushort* outw_bf = (ushort*)p;  p += (size_t)D_ * E_ * 2;
    ushort* yg_bf   = (ushort*)p;  p += (size_t)M * E_ * 2;
    float*  skipb   = (float*)p;   p += (size_t)M * E_ * 4;
    float*  xin     = (float*)p;   p += (size_t)M * E_ * 4;   // also delta (alias, disjoint lifetime)
    float*  xs      = (float*)p;   p += (size_t)M * E_ * 4;
    float*  d1      = (float*)p;   p += (size_t)M * DD_ * 4;
    float*  Bm      = (float*)p;   p += (size_t)M * 16 * 4;
    float*  Cm      = (float*)p;   p += (size_t)M * 16 * 4;
    float*  delta   = xin;

    dim3 blk(256);

    // weight casts (6M elems total)
    k_cast_bf<<<dim3((E_ * D_) / 1024), blk, 0, stream>>>(skip_w, skw_bf);
    k_cast_bf<<<dim3((E_ * D_) / 1024), blk, 0, stream>>>(in_w, inw_bf);
    k_cast_bf<<<dim3((D_ * E_) / 1024), blk, 0, stream>>>(out_w, outw_bf);
    // 1. RMSNorm -> bf16
    k_rmsnorm_bf<<<dim3(M), blk, 0, stream>>>(resid, norm_w, xn_bf);
    // 2. skip = xn @ skip_w^T   [M,E]  (bf16 MFMA)
    k_gemm_bf<0><<<dim3(E_ / 128, M / 128), blk, 0, stream>>>(xn_bf, skw_bf, nullptr, skipb, M, E_, D_);
    // 3. xin = xn @ in_w^T      [M,E]  (bf16 MFMA)
    k_gemm_bf<0><<<dim3(E_ / 128, M / 128), blk, 0, stream>>>(xn_bf, inw_bf, nullptr, xin, M, E_, D_);
    // 4. xs = silu(conv(xin)+b)
    k_conv_silu<<<dim3((M * E_) / 256), blk, 0, stream>>>(xin, conv_w, conv_b, xs);
    // 5. d1 = xs @ Wd1^T        [M,64]
    k_gemm_tn<0><<<dim3(DD_ / 64, M / 64), blk, 0, stream>>>(xs, Wd1, nullptr, d1, M, DD_, E_);
    // 6. delta = softplus(d1 @ Wd2^T + b) [M,E]
    k_gemm_tn<1><<<dim3(E_ / 64, M / 64), blk, 0, stream>>>(d1, Wd2_w, Wd2_b, delta, M, E_, DD_);
    // 7. Bm, Cm
    k_bc<<<dim3(M / 8), blk, 0, stream>>>(xs, WB, WC, Bm, Cm);
    // 8. scan (fused W_D skip-add + silu(skip) gate), writes bf16
    k_scan16<<<dim3((B_ * E_) / 16), blk, 0, stream>>>(xs, delta, Bm, Cm, A_log, W_D, skipb, yg_bf);
    // 9. out = resid + yg @ out_w^T  (bf16 MFMA)
    k_gemm_bf<2><<<dim3(D_ / 128, M / 128), blk, 0, stream>>>(yg_bf, outw_bf, resid, out, M, D_, E_);
}

// Round 3
// 1352.060 us; speedup vs baseline: 2.4638x; 1.7151x over previous
//
#include <hip/hip_runtime.h>
#include <hip/hip_bf16.h>
#include <math.h>

#define B_ 4
#define L_ 2048
#define D_ 1024
#define E_ 2048
#define N_ 16
#define DD_ 64
#define DCONV_ 4

typedef __attribute__((ext_vector_type(8))) short bf16x8;
typedef __attribute__((ext_vector_type(4))) float f32x4;

static __device__ __forceinline__ float silu_f(float x) {
    return x / (1.f + __expf(-x));
}

static __device__ __forceinline__ ushort f2bf(float f) {
    __hip_bfloat16 h = __float2bfloat16(f);
    return *reinterpret_cast<ushort*>(&h);
}

// ---------------- RMSNorm: resid [B*L, D] -> xn (bf16) ----------------
__global__ __launch_bounds__(256) void k_rmsnorm_bf(const float* __restrict__ resid,
                                                    const float* __restrict__ nw,
                                                    ushort* __restrict__ out) {
    int row = blockIdx.x;
    const float* r = resid + (size_t)row * D_;
    int t = threadIdx.x;
    float4 v = *reinterpret_cast<const float4*>(&r[t * 4]);
    float ss = v.x * v.x + v.y * v.y + v.z * v.z + v.w * v.w;
#pragma unroll
    for (int o = 32; o >= 1; o >>= 1) ss += __shfl_xor(ss, o, 64);
    __shared__ float red[4];
    if ((t & 63) == 0) red[t >> 6] = ss;
    __syncthreads();
    float tot = red[0] + red[1] + red[2] + red[3];
    float rs = rsqrtf(tot * (1.f / (float)D_) + 1e-5f);
    float4 w4 = *reinterpret_cast<const float4*>(&nw[t * 4]);
    ushort4 o4;
    o4.x = f2bf(v.x * rs * w4.x);
    o4.y = f2bf(v.y * rs * w4.y);
    o4.z = f2bf(v.z * rs * w4.z);
    o4.w = f2bf(v.w * rs * w4.w);
    *reinterpret_cast<ushort4*>(&out[(size_t)row * D_ + t * 4]) = o4;
}

// ---------------- f32 -> bf16 cast (for weights) ----------------
__global__ __launch_bounds__(256) void k_cast_bf(const float* __restrict__ in,
                                                 ushort* __restrict__ out) {
    int i = blockIdx.x * 256 + threadIdx.x;  // float4 index
    float4 v = *reinterpret_cast<const float4*>(&in[i * 4]);
    ushort4 o;
    o.x = f2bf(v.x); o.y = f2bf(v.y); o.z = f2bf(v.z); o.w = f2bf(v.w);
    *reinterpret_cast<ushort4*>(&out[i * 4]) = o;
}

// ---------------- bf16 MFMA GEMM: C[M,N] = A[M,K] @ W[N,K]^T ----------------
// EPI: 0 = plain f32 store, 2 = += addsrc (residual) then f32 store
template <int EPI>
__global__ __launch_bounds__(256) void k_gemm_bf(const ushort* __restrict__ A,
                                                 const ushort* __restrict__ W,
                                                 const float* __restrict__ addsrc,
                                                 float* __restrict__ C,
                                                 int M, int N, int K) {
    constexpr int BM = 128, BN = 128, BK = 32, LDB = 40;  // 40 bf16 = 80B row stride
    __shared__ __align__(16) ushort As[BM * LDB];
    __shared__ __align__(16) ushort Ws[BN * LDB];
    int t = threadIdx.x;
    int m0 = blockIdx.y * BM, n0 = blockIdx.x * BN;
    int wave = t >> 6, lane = t & 63;
    int wr = wave >> 1, wc = wave & 1;     // wave quadrant (64x64)
    int lr = lane & 15, lg = lane >> 4;    // frag row/col, k-group

    f32x4 acc[4][4] = {};

    for (int k0 = 0; k0 < K; k0 += BK) {
#pragma unroll
        for (int p = 0; p < 2; ++p) {
            int f = t + p * 256;           // 16B chunk id, 0..511
            int row = f >> 2;              // 0..127
            int cg = (f & 3) * 8;          // bf16 col 0,8,16,24
            *reinterpret_cast<uint4*>(&As[row * LDB + cg]) =
                *reinterpret_cast<const uint4*>(&A[(size_t)(m0 + row) * K + k0 + cg]);
            *reinterpret_cast<uint4*>(&Ws[row * LDB + cg]) =
                *reinterpret_cast<const uint4*>(&W[(size_t)(n0 + row) * K + k0 + cg]);
        }
        __syncthreads();
        bf16x8 af[4], bfr[4];
#pragma unroll
        for (int i = 0; i < 4; ++i) {
            af[i]  = *reinterpret_cast<const bf16x8*>(&As[(wr * 64 + i * 16 + lr) * LDB + lg * 8]);
            bfr[i] = *reinterpret_cast<const bf16x8*>(&Ws[(wc * 64 + i * 16 + lr) * LDB + lg * 8]);
        }
#pragma unroll
        for (int i = 0; i < 4; ++i)
#pragma unroll
            for (int j = 0; j < 4; ++j)
                acc[i][j] = __builtin_amdgcn_mfma_f32_16x16x32_bf16(af[i], bfr[j], acc[i][j], 0, 0, 0);
        __syncthreads();
    }

#pragma unroll
    for (int i = 0; i < 4; ++i) {
        int mrow = m0 + wr * 64 + i * 16 + lg * 4;
#pragma unroll
        for (int j = 0; j < 4; ++j) {
            int ncol = n0 + wc * 64 + j * 16 + lr;
#pragma unroll
            for (int q = 0; q < 4; ++q) {
                float v = acc[i][j][q];
                size_t idx = (size_t)(mrow + q) * N + ncol;
                if (EPI == 2) v += addsrc[idx];
                C[idx] = v;
            }
        }
    }
}

// ---------------- f32 GEMM (small projections) ----------------
// EPI: 0 = none, 1 = softplus(acc + bias[n])
template <int EPI>
__global__ __launch_bounds__(256) void k_gemm_tn(const float* __restrict__ A,
                                                 const float* __restrict__ W,
                                                 const float* __restrict__ bias,
                                                 float* __restrict__ C,
                                                 int M, int N, int K) {
    constexpr int BM = 64, BN = 64, BK = 32;
    constexpr int LDP = 68;
    __shared__ __align__(16) float As[BK][LDP];
    __shared__ __align__(16) float Ws[BK][LDP];
    int tid = threadIdx.x;
    int tx = tid & 15;
    int ty = tid >> 4;
    int m0 = blockIdx.y * BM;
    int n0 = blockIdx.x * BN;

    float acc[4][4];
#pragma unroll
    for (int i = 0; i < 4; ++i)
#pragma unroll
        for (int j = 0; j < 4; ++j) acc[i][j] = 0.f;

    for (int k0 = 0; k0 < K; k0 += BK) {
#pragma unroll
        for (int p = 0; p < 2; ++p) {
            int idx = tid + p * 256;
            int row = idx >> 3;
            int col4 = (idx & 7) * 4;
            float4 av = *reinterpret_cast<const float4*>(&A[(size_t)(m0 + row) * K + k0 + col4]);
            As[col4 + 0][row] = av.x;
            As[col4 + 1][row] = av.y;
            As[col4 + 2][row] = av.z;
            As[col4 + 3][row] = av.w;
            float4 wv = *reinterpret_cast<const float4*>(&W[(size_t)(n0 + row) * K + k0 + col4]);
            Ws[col4 + 0][row] = wv.x;
            Ws[col4 + 1][row] = wv.y;
            Ws[col4 + 2][row] = wv.z;
            Ws[col4 + 3][row] = wv.w;
        }
        __syncthreads();
#pragma unroll
        for (int kk = 0; kk < BK; ++kk) {
            float4 a4 = *reinterpret_cast<const float4*>(&As[kk][ty * 4]);
            float4 b4 = *reinterpret_cast<const float4*>(&Ws[kk][tx * 4]);
            float a[4] = {a4.x, a4.y, a4.z, a4.w};
            float b[4] = {b4.x, b4.y, b4.z, b4.w};
#pragma unroll
            for (int i = 0; i < 4; ++i)
#pragma unroll
                for (int j = 0; j < 4; ++j) acc[i][j] = fmaf(a[i], b[j], acc[i][j]);
        }
        __syncthreads();
    }

#pragma unroll
    for (int i = 0; i < 4; ++i) {
        int m = m0 + ty * 4 + i;
        int nbase = n0 + tx * 4;
        float4 o4;
        float vals[4];
#pragma unroll
        for (int j = 0; j < 4; ++j) {
            float v = acc[i][j];
            if (EPI == 1) {
                float z = v + bias[nbase + j];
                vals[j] = (z > 20.f) ? z : log1pf(expf(z));
            } else {
                vals[j] = v;
            }
        }
        o4.x = vals[0]; o4.y = vals[1]; o4.z = vals[2]; o4.w = vals[3];
        *reinterpret_cast<float4*>(&C[(size_t)m * N + nbase]) = o4;
    }
}

// ---------------- depthwise causal conv1d + bias + silu ----------------
__global__ __launch_bounds__(256) void k_conv_silu(const float* __restrict__ x,
                                                   const float* __restrict__ w,
                                                   const float* __restrict__ bias,
                                                   float* __restrict__ out) {
    int idx = blockIdx.x * 256 + threadIdx.x;
    int e = idx & (E_ - 1);
    int l = (idx / E_) & (L_ - 1);
    float4 wv = *reinterpret_cast<const float4*>(&w[e * 4]);
    float acc = bias[e];
    acc = fmaf(wv.w, x[idx], acc);
    if (l >= 1) acc = fmaf(wv.z, x[idx - E_], acc);
    if (l >= 2) acc = fmaf(wv.y, x[idx - 2 * E_], acc);
    if (l >= 3) acc = fmaf(wv.x, x[idx - 3 * E_], acc);
    out[idx] = silu_f(acc);
}

// ---------------- B/C projections ----------------
__global__ __launch_bounds__(256) void k_bc(const float* __restrict__ xs,
                                            const float* __restrict__ WB,
                                            const float* __restrict__ WC,
                                            float* __restrict__ Bm,
                                            float* __restrict__ Cm) {
    int tid = threadIdx.x;
    int n = tid & 31;
    int mi = tid >> 5;
    int m = blockIdx.x * 8 + mi;
    const float* xr = xs + (size_t)m * E_;
    const float* wr = (n < 16) ? (WB + (size_t)n * E_) : (WC + (size_t)(n - 16) * E_);
    float acc = 0.f;
    for (int k = 0; k < E_; k += 4) {
        float4 xv = *reinterpret_cast<const float4*>(&xr[k]);
        float4 wv = *reinterpret_cast<const float4*>(&wr[k]);
        acc = fmaf(xv.x, wv.x, acc);
        acc = fmaf(xv.y, wv.y, acc);
        acc = fmaf(xv.z, wv.z, acc);
        acc = fmaf(xv.w, wv.w, acc);
    }
    if (n < 16) Bm[(size_t)m * 16 + n] = acc;
    else        Cm[(size_t)m * 16 + (n - 16)] = acc;
}

// ---------------- selective scan, LDS-chunked ----------------
// Block: 16 channels (one b), 256 threads: ci = t>>4 (channel), n = t&15 (state).
// Chunks of CL=128 timesteps staged into LDS with coalesced loads.
#define CL_ 128
__global__ __launch_bounds__(256) void k_scan_lds(const float* __restrict__ xs,
                                                  const float* __restrict__ delta,
                                                  const float* __restrict__ Bm,
                                                  const float* __restrict__ Cm,
                                                  const float* __restrict__ A_log,
                                                  const float* __restrict__ W_D,
                                                  const float* __restrict__ skip,
                                                  ushort* __restrict__ yg) {
    __shared__ __align__(16) float sd[CL_][16];
    __shared__ __align__(16) float sx[CL_][16];
    __shared__ __align__(16) float sk_[CL_][16];
    __shared__ __align__(16) float sB[CL_][16];
    __shared__ __align__(16) float sC[CL_][16];
    __shared__ __align__(16) ushort syg[CL_][16];

    int t = threadIdx.x;
    int n = t & 15;
    int ci = t >> 4;
    int b  = blockIdx.x >> 7;              // / (E/16)
    int e0 = (blockIdx.x & 127) * 16;
    int e  = e0 + ci;

    float A = -__expf(A_log[e * 16 + n]);
    float wd = W_D[e];
    float h = 0.f;

    for (int l0 = 0; l0 < L_; l0 += CL_) {
        size_t rowbase = (size_t)b * L_ + l0;
        // ---- stage (coalesced float4) ----
#pragma unroll
        for (int p = 0; p < 2; ++p) {
            int f = t + p * 256;           // 0..511
            int l = f >> 2;
            int q = (f & 3) * 4;
            size_t g = (rowbase + l) * E_ + e0 + q;
            *reinterpret_cast<float4*>(&sd[l][q])  = *reinterpret_cast<const float4*>(&delta[g]);
            *reinterpret_cast<float4*>(&sx[l][q])  = *reinterpret_cast<const float4*>(&xs[g]);
            *reinterpret_cast<float4*>(&sk_[l][q]) = *reinterpret_cast<const float4*>(&skip[g]);
            size_t gb = (rowbase + l) * 16 + q;
            *reinterpret_cast<float4*>(&sB[l][q])  = *reinterpret_cast<const float4*>(&Bm[gb]);
            *reinterpret_cast<float4*>(&sC[l][q])  = *reinterpret_cast<const float4*>(&Cm[gb]);
        }
        __syncthreads();
        // ---- scan the chunk from LDS ----
#pragma unroll 4
        for (int l = 0; l < CL_; ++l) {
            float d  = sd[l][ci];
            float xv = sx[l][ci];
            float Bv = sB[l][n];
            float Cv = sC[l][n];
            h = fmaf(__expf(d * A), h, d * xv * Bv);
            float y = h * Cv;
            y += __shfl_xor(y, 1, 64);
            y += __shfl_xor(y, 2, 64);
            y += __shfl_xor(y, 4, 64);
            y += __shfl_xor(y, 8, 64);
            if (n == 0) {
                float g = silu_f(sk_[l][ci]);
                syg[l][ci] = f2bf((y + xv * wd) * g);
            }
        }
        __syncthreads();
        // ---- coalesced bf16 writeback ----
        {
            int l = t >> 1;
            int half = (t & 1) * 8;
            *reinterpret_cast<uint4*>(&yg[(rowbase + l) * E_ + e0 + half]) =
                *reinterpret_cast<const uint4*>(&syg[l][half]);
        }
    }
}

extern "C" void kernel_launch(void* const* d_in, const int* in_sizes, int n_in,
                              void* d_out, int out_size, void* d_ws, size_t ws_size,
                              hipStream_t stream) {
    const float* resid  = (const float*)d_in[0];
    const float* norm_w = (const float*)d_in[1];
    const float* skip_w = (const float*)d_in[2];
    const float* in_w   = (const float*)d_in[3];
    const float* conv_w = (const float*)d_in[4];
    const float* conv_b = (const float*)d_in[5];
    const float* Wd1    = (const float*)d_in[6];
    const float* Wd2_w  = (const float*)d_in[7];
    const float* Wd2_b  = (const float*)d_in[8];
    const float* WB     = (const float*)d_in[9];
    const float* WC     = (const float*)d_in[10];
    const float* A_log  = (const float*)d_in[11];
    const float* W_D    = (const float*)d_in[12];
    const float* out_w  = (const float*)d_in[13];
    float* out = (float*)d_out;

    const int M = B_ * L_;                 // 8192
    char* p = (char*)d_ws;
    ushort* xn_bf   = (ushort*)p;  p += (size_t)M * D_ * 2;   // RMSNorm out (bf16)
    ushort* skw_bf  = (ushort*)p;  p += (size_t)E_ * D_ * 2;
    ushort* inw_bf  = (ushort*)p;  p += (size_t)E_ * D_ * 2;
    ushort* outw_bf = (ushort*)p;  p += (size_t)D_ * E_ * 2;
    ushort* yg_bf   = (ushort*)p;  p += (size_t)M * E_ * 2;
    float*  skipb   = (float*)p;   p += (size_t)M * E_ * 4;
    float*  xin     = (float*)p;   p += (size_t)M * E_ * 4;   // also delta (alias, disjoint lifetime)
    float*  xs      = (float*)p;   p += (size_t)M * E_ * 4;
    float*  d1      = (float*)p;   p += (size_t)M * DD_ * 4;
    float*  Bm      = (float*)p;   p += (size_t)M * 16 * 4;
    float*  Cm      = (float*)p;   p += (size_t)M * 16 * 4;
    float*  delta   = xin;

    dim3 blk(256);

    // weight casts (6M elems total)
    k_cast_bf<<<dim3((E_ * D_) / 1024), blk, 0, stream>>>(skip_w, skw_bf);
    k_cast_bf<<<dim3((E_ * D_) / 1024), blk, 0, stream>>>(in_w, inw_bf);
    k_cast_bf<<<dim3((D_ * E_) / 1024), blk, 0, stream>>>(out_w, outw_bf);
    // 1. RMSNorm -> bf16
    k_rmsnorm_bf<<<dim3(M), blk, 0, stream>>>(resid, norm_w, xn_bf);
    // 2. skip = xn @ skip_w^T   [M,E]  (bf16 MFMA)
    k_gemm_bf<0><<<dim3(E_ / 128, M / 128), blk, 0, stream>>>(xn_bf, skw_bf, nullptr, skipb, M, E_, D_);
    // 3. xin = xn @ in_w^T      [M,E]  (bf16 MFMA)
    k_gemm_bf<0><<<dim3(E_ / 128, M / 128), blk, 0, stream>>>(xn_bf, inw_bf, nullptr, xin, M, E_, D_);
    // 4. xs = silu(conv(xin)+b)
    k_conv_silu<<<dim3((M * E_) / 256), blk, 0, stream>>>(xin, conv_w, conv_b, xs);
    // 5. d1 = xs @ Wd1^T        [M,64]
    k_gemm_tn<0><<<dim3(DD_ / 64, M / 64), blk, 0, stream>>>(xs, Wd1, nullptr, d1, M, DD_, E_);
    // 6. delta = softplus(d1 @ Wd2^T + b) [M,E]
    k_gemm_tn<1><<<dim3(E_ / 64, M / 64), blk, 0, stream>>>(d1, Wd2_w, Wd2_b, delta, M, E_, DD_);
    // 7. Bm, Cm
    k_bc<<<dim3(M / 8), blk, 0, stream>>>(xs, WB, WC, Bm, Cm);
    // 8. scan (LDS-chunked; fused W_D skip-add + silu(skip) gate), writes bf16
    k_scan_lds<<<dim3(B_ * (E_ / 16)), blk, 0, stream>>>(xs, delta, Bm, Cm, A_log, W_D, skipb, yg_bf);
    // 9. out = resid + yg @ out_w^T  (bf16 MFMA)
    k_gemm_bf<2><<<dim3(D_ / 128, M / 128), blk, 0, stream>>>(yg_bf, outw_bf, resid, out, M, D_, E_);
}

// Round 4
// 1005.811 us; speedup vs baseline: 3.3120x; 1.3442x over previous
//
#include <hip/hip_runtime.h>
#include <hip/hip_bf16.h>
#include <math.h>

#define B_ 4
#define L_ 2048
#define D_ 1024
#define E_ 2048
#define N_ 16
#define DD_ 64
#define DCONV_ 4

#define S_SEG 8
#define SEGLEN_ (L_ / S_SEG)   // 256
#define CL_ 32

typedef __attribute__((ext_vector_type(8))) short bf16x8;
typedef __attribute__((ext_vector_type(4))) float f32x4;

static __device__ __forceinline__ float silu_f(float x) {
    return x / (1.f + __expf(-x));
}

static __device__ __forceinline__ ushort f2bf(float f) {
    __hip_bfloat16 h = __float2bfloat16(f);
    return *reinterpret_cast<ushort*>(&h);
}

// ---------------- RMSNorm: resid [B*L, D] -> xn (bf16) ----------------
__global__ __launch_bounds__(256) void k_rmsnorm_bf(const float* __restrict__ resid,
                                                    const float* __restrict__ nw,
                                                    ushort* __restrict__ out) {
    int row = blockIdx.x;
    const float* r = resid + (size_t)row * D_;
    int t = threadIdx.x;
    float4 v = *reinterpret_cast<const float4*>(&r[t * 4]);
    float ss = v.x * v.x + v.y * v.y + v.z * v.z + v.w * v.w;
#pragma unroll
    for (int o = 32; o >= 1; o >>= 1) ss += __shfl_xor(ss, o, 64);
    __shared__ float red[4];
    if ((t & 63) == 0) red[t >> 6] = ss;
    __syncthreads();
    float tot = red[0] + red[1] + red[2] + red[3];
    float rs = rsqrtf(tot * (1.f / (float)D_) + 1e-5f);
    float4 w4 = *reinterpret_cast<const float4*>(&nw[t * 4]);
    ushort4 o4;
    o4.x = f2bf(v.x * rs * w4.x);
    o4.y = f2bf(v.y * rs * w4.y);
    o4.z = f2bf(v.z * rs * w4.z);
    o4.w = f2bf(v.w * rs * w4.w);
    *reinterpret_cast<ushort4*>(&out[(size_t)row * D_ + t * 4]) = o4;
}

// ---------------- f32 -> bf16 cast (for weights) ----------------
__global__ __launch_bounds__(256) void k_cast_bf(const float* __restrict__ in,
                                                 ushort* __restrict__ out) {
    int i = blockIdx.x * 256 + threadIdx.x;  // float4 index
    float4 v = *reinterpret_cast<const float4*>(&in[i * 4]);
    ushort4 o;
    o.x = f2bf(v.x); o.y = f2bf(v.y); o.z = f2bf(v.z); o.w = f2bf(v.w);
    *reinterpret_cast<ushort4*>(&out[i * 4]) = o;
}

// ---------------- bf16 MFMA GEMM: C[M,N] = A[M,K] @ W[N,K]^T ----------------
// EPI: 0 = plain f32 store, 2 = += addsrc (residual) then f32 store
template <int EPI>
__global__ __launch_bounds__(256) void k_gemm_bf(const ushort* __restrict__ A,
                                                 const ushort* __restrict__ W,
                                                 const float* __restrict__ addsrc,
                                                 float* __restrict__ C,
                                                 int M, int N, int K) {
    constexpr int BM = 128, BN = 128, BK = 32, LDB = 40;  // 40 bf16 = 80B row stride
    __shared__ __align__(16) ushort As[BM * LDB];
    __shared__ __align__(16) ushort Ws[BN * LDB];
    int t = threadIdx.x;
    int m0 = blockIdx.y * BM, n0 = blockIdx.x * BN;
    int wave = t >> 6, lane = t & 63;
    int wr = wave >> 1, wc = wave & 1;     // wave quadrant (64x64)
    int lr = lane & 15, lg = lane >> 4;    // frag row/col, k-group

    f32x4 acc[4][4] = {};

    for (int k0 = 0; k0 < K; k0 += BK) {
#pragma unroll
        for (int p = 0; p < 2; ++p) {
            int f = t + p * 256;           // 16B chunk id, 0..511
            int row = f >> 2;              // 0..127
            int cg = (f & 3) * 8;          // bf16 col 0,8,16,24
            *reinterpret_cast<uint4*>(&As[row * LDB + cg]) =
                *reinterpret_cast<const uint4*>(&A[(size_t)(m0 + row) * K + k0 + cg]);
            *reinterpret_cast<uint4*>(&Ws[row * LDB + cg]) =
                *reinterpret_cast<const uint4*>(&W[(size_t)(n0 + row) * K + k0 + cg]);
        }
        __syncthreads();
        bf16x8 af[4], bfr[4];
#pragma unroll
        for (int i = 0; i < 4; ++i) {
            af[i]  = *reinterpret_cast<const bf16x8*>(&As[(wr * 64 + i * 16 + lr) * LDB + lg * 8]);
            bfr[i] = *reinterpret_cast<const bf16x8*>(&Ws[(wc * 64 + i * 16 + lr) * LDB + lg * 8]);
        }
#pragma unroll
        for (int i = 0; i < 4; ++i)
#pragma unroll
            for (int j = 0; j < 4; ++j)
                acc[i][j] = __builtin_amdgcn_mfma_f32_16x16x32_bf16(af[i], bfr[j], acc[i][j], 0, 0, 0);
        __syncthreads();
    }

#pragma unroll
    for (int i = 0; i < 4; ++i) {
        int mrow = m0 + wr * 64 + i * 16 + lg * 4;
#pragma unroll
        for (int j = 0; j < 4; ++j) {
            int ncol = n0 + wc * 64 + j * 16 + lr;
#pragma unroll
            for (int q = 0; q < 4; ++q) {
                float v = acc[i][j][q];
                size_t idx = (size_t)(mrow + q) * N + ncol;
                if (EPI == 2) v += addsrc[idx];
                C[idx] = v;
            }
        }
    }
}

// ---------------- f32 GEMM (small projections) ----------------
// EPI: 0 = none, 1 = softplus(acc + bias[n])
template <int EPI>
__global__ __launch_bounds__(256) void k_gemm_tn(const float* __restrict__ A,
                                                 const float* __restrict__ W,
                                                 const float* __restrict__ bias,
                                                 float* __restrict__ C,
                                                 int M, int N, int K) {
    constexpr int BM = 64, BN = 64, BK = 32;
    constexpr int LDP = 68;
    __shared__ __align__(16) float As[BK][LDP];
    __shared__ __align__(16) float Ws[BK][LDP];
    int tid = threadIdx.x;
    int tx = tid & 15;
    int ty = tid >> 4;
    int m0 = blockIdx.y * BM;
    int n0 = blockIdx.x * BN;

    float acc[4][4];
#pragma unroll
    for (int i = 0; i < 4; ++i)
#pragma unroll
        for (int j = 0; j < 4; ++j) acc[i][j] = 0.f;

    for (int k0 = 0; k0 < K; k0 += BK) {
#pragma unroll
        for (int p = 0; p < 2; ++p) {
            int idx = tid + p * 256;
            int row = idx >> 3;
            int col4 = (idx & 7) * 4;
            float4 av = *reinterpret_cast<const float4*>(&A[(size_t)(m0 + row) * K + k0 + col4]);
            As[col4 + 0][row] = av.x;
            As[col4 + 1][row] = av.y;
            As[col4 + 2][row] = av.z;
            As[col4 + 3][row] = av.w;
            float4 wv = *reinterpret_cast<const float4*>(&W[(size_t)(n0 + row) * K + k0 + col4]);
            Ws[col4 + 0][row] = wv.x;
            Ws[col4 + 1][row] = wv.y;
            Ws[col4 + 2][row] = wv.z;
            Ws[col4 + 3][row] = wv.w;
        }
        __syncthreads();
#pragma unroll
        for (int kk = 0; kk < BK; ++kk) {
            float4 a4 = *reinterpret_cast<const float4*>(&As[kk][ty * 4]);
            float4 b4 = *reinterpret_cast<const float4*>(&Ws[kk][tx * 4]);
            float a[4] = {a4.x, a4.y, a4.z, a4.w};
            float b[4] = {b4.x, b4.y, b4.z, b4.w};
#pragma unroll
            for (int i = 0; i < 4; ++i)
#pragma unroll
                for (int j = 0; j < 4; ++j) acc[i][j] = fmaf(a[i], b[j], acc[i][j]);
        }
        __syncthreads();
    }

#pragma unroll
    for (int i = 0; i < 4; ++i) {
        int m = m0 + ty * 4 + i;
        int nbase = n0 + tx * 4;
        float4 o4;
        float vals[4];
#pragma unroll
        for (int j = 0; j < 4; ++j) {
            float v = acc[i][j];
            if (EPI == 1) {
                float z = v + bias[nbase + j];
                vals[j] = (z > 20.f) ? z : log1pf(expf(z));
            } else {
                vals[j] = v;
            }
        }
        o4.x = vals[0]; o4.y = vals[1]; o4.z = vals[2]; o4.w = vals[3];
        *reinterpret_cast<float4*>(&C[(size_t)m * N + nbase]) = o4;
    }
}

// ---------------- depthwise causal conv1d + bias + silu ----------------
__global__ __launch_bounds__(256) void k_conv_silu(const float* __restrict__ x,
                                                   const float* __restrict__ w,
                                                   const float* __restrict__ bias,
                                                   float* __restrict__ out) {
    int idx = blockIdx.x * 256 + threadIdx.x;
    int e = idx & (E_ - 1);
    int l = (idx / E_) & (L_ - 1);
    float4 wv = *reinterpret_cast<const float4*>(&w[e * 4]);
    float acc = bias[e];
    acc = fmaf(wv.w, x[idx], acc);
    if (l >= 1) acc = fmaf(wv.z, x[idx - E_], acc);
    if (l >= 2) acc = fmaf(wv.y, x[idx - 2 * E_], acc);
    if (l >= 3) acc = fmaf(wv.x, x[idx - 3 * E_], acc);
    out[idx] = silu_f(acc);
}

// ---------------- B/C projections ----------------
__global__ __launch_bounds__(256) void k_bc(const float* __restrict__ xs,
                                            const float* __restrict__ WB,
                                            const float* __restrict__ WC,
                                            float* __restrict__ Bm,
                                            float* __restrict__ Cm) {
    int tid = threadIdx.x;
    int n = tid & 31;
    int mi = tid >> 5;
    int m = blockIdx.x * 8 + mi;
    const float* xr = xs + (size_t)m * E_;
    const float* wr = (n < 16) ? (WB + (size_t)n * E_) : (WC + (size_t)(n - 16) * E_);
    float acc = 0.f;
    for (int k = 0; k < E_; k += 4) {
        float4 xv = *reinterpret_cast<const float4*>(&xr[k]);
        float4 wv = *reinterpret_cast<const float4*>(&wr[k]);
        acc = fmaf(xv.x, wv.x, acc);
        acc = fmaf(xv.y, wv.y, acc);
        acc = fmaf(xv.z, wv.z, acc);
        acc = fmaf(xv.w, wv.w, acc);
    }
    if (n < 16) Bm[(size_t)m * 16 + n] = acc;
    else        Cm[(size_t)m * 16 + (n - 16)] = acc;
}

// ================= segmented selective scan =================
// Decomposition: h after segment s = h_loc[s] + exp(A*sum(delta_seg)) * h_in[s].
// Pass1: per-segment local scan (h0=0) -> h_loc, sum(delta).  Pass2: chain
// segments serially (tiny).  Pass3: full scan per segment with h_in, gated out.
// Layout (p1/p3): 256 thr = 64 channels x 4 lanes; lane q owns states 4q..4q+3.

__global__ __launch_bounds__(256) void k_scan_p1(const float* __restrict__ xs,
                                                 const float* __restrict__ delta,
                                                 const float* __restrict__ Bm,
                                                 const float* __restrict__ A_log,
                                                 float* __restrict__ hloc,
                                                 float* __restrict__ sdsum) {
    __shared__ __align__(16) float sd[CL_][64];
    __shared__ __align__(16) float sx[CL_][64];
    __shared__ __align__(16) float sB[CL_][16];
    int t = threadIdx.x;
    int q = t & 3, ci = t >> 2;
    int bid = blockIdx.x;
    int s = bid & 7;
    int eblk = (bid >> 3) & 31;
    int b = bid >> 8;
    int e0 = eblk * 64;
    int e = e0 + ci;

    f32x4 A4;
    {
        f32x4 al = *reinterpret_cast<const f32x4*>(&A_log[e * 16 + q * 4]);
#pragma unroll
        for (int i = 0; i < 4; ++i) A4[i] = -__expf(al[i]);
    }
    f32x4 h = {0.f, 0.f, 0.f, 0.f};
    float sdl = 0.f;

    for (int l0 = 0; l0 < SEGLEN_; l0 += CL_) {
        size_t rowbase = (size_t)b * L_ + s * SEGLEN_ + l0;
#pragma unroll
        for (int p = 0; p < 2; ++p) {
            int f = t + p * 256;
            int l = f >> 4;
            int c4 = (f & 15) * 4;
            size_t g = (rowbase + l) * E_ + e0 + c4;
            *reinterpret_cast<f32x4*>(&sd[l][c4]) = *reinterpret_cast<const f32x4*>(&delta[g]);
            *reinterpret_cast<f32x4*>(&sx[l][c4]) = *reinterpret_cast<const f32x4*>(&xs[g]);
        }
        if (t < 128) {
            int l = t >> 2;
            int c4 = (t & 3) * 4;
            *reinterpret_cast<f32x4*>(&sB[l][c4]) =
                *reinterpret_cast<const f32x4*>(&Bm[(rowbase + l) * 16 + c4]);
        }
        __syncthreads();
#pragma unroll 4
        for (int l = 0; l < CL_; ++l) {
            float d = sd[l][ci];
            float xv = sx[l][ci];
            f32x4 Bv = *reinterpret_cast<const f32x4*>(&sB[l][q * 4]);
            f32x4 e4;
#pragma unroll
            for (int i = 0; i < 4; ++i) e4[i] = __expf(d * A4[i]);
            float dx = d * xv;
            h = e4 * h + dx * Bv;
            sdl += d;
        }
        __syncthreads();
    }
    size_t idx = (size_t)(b * S_SEG + s) * E_ + e;
    *reinterpret_cast<f32x4*>(&hloc[idx * 16 + q * 4]) = h;
    if (q == 0) sdsum[idx] = sdl;
}

__global__ __launch_bounds__(256) void k_scan_p2(const float* __restrict__ hloc,
                                                 const float* __restrict__ sdsum,
                                                 const float* __restrict__ A_log,
                                                 float* __restrict__ hin) {
    int t = blockIdx.x * 256 + threadIdx.x;   // B*E*4 threads
    int q = t & 3;
    int e = (t >> 2) & (E_ - 1);
    int b = t >> 13;
    f32x4 A4;
    {
        f32x4 al = *reinterpret_cast<const f32x4*>(&A_log[e * 16 + q * 4]);
#pragma unroll
        for (int i = 0; i < 4; ++i) A4[i] = -__expf(al[i]);
    }
    f32x4 acc = {0.f, 0.f, 0.f, 0.f};
#pragma unroll
    for (int s = 0; s < S_SEG; ++s) {
        size_t idx = (size_t)(b * S_SEG + s) * E_ + e;
        *reinterpret_cast<f32x4*>(&hin[idx * 16 + q * 4]) = acc;
        float sd = sdsum[idx];
        f32x4 hl = *reinterpret_cast<const f32x4*>(&hloc[idx * 16 + q * 4]);
        f32x4 p;
#pragma unroll
        for (int i = 0; i < 4; ++i) p[i] = __expf(A4[i] * sd);
        acc = hl + p * acc;
    }
}

__global__ __launch_bounds__(256) void k_scan_p3(const float* __restrict__ xs,
                                                 const float* __restrict__ delta,
                                                 const float* __restrict__ Bm,
                                                 const float* __restrict__ Cm,
                                                 const float* __restrict__ A_log,
                                                 const float* __restrict__ W_D,
                                                 const float* __restrict__ skip,
                                                 const float* __restrict__ hin,
                                                 ushort* __restrict__ yg) {
    __shared__ __align__(16) float sd[CL_][64];
    __shared__ __align__(16) float sx[CL_][64];
    __shared__ __align__(16) float ssk[CL_][64];
    __shared__ __align__(16) float sB[CL_][16];
    __shared__ __align__(16) float sC[CL_][16];
    __shared__ __align__(16) ushort syg[CL_][64];
    int t = threadIdx.x;
    int q = t & 3, ci = t >> 2;
    int bid = blockIdx.x;
    int s = bid & 7;
    int eblk = (bid >> 3) & 31;
    int b = bid >> 8;
    int e0 = eblk * 64;
    int e = e0 + ci;

    f32x4 A4;
    {
        f32x4 al = *reinterpret_cast<const f32x4*>(&A_log[e * 16 + q * 4]);
#pragma unroll
        for (int i = 0; i < 4; ++i) A4[i] = -__expf(al[i]);
    }
    size_t cidx = (size_t)(b * S_SEG + s) * E_ + e;
    f32x4 h = *reinterpret_cast<const f32x4*>(&hin[cidx * 16 + q * 4]);
    float wd = W_D[e];

    for (int l0 = 0; l0 < SEGLEN_; l0 += CL_) {
        size_t rowbase = (size_t)b * L_ + s * SEGLEN_ + l0;
#pragma unroll
        for (int p = 0; p < 2; ++p) {
            int f = t + p * 256;
            int l = f >> 4;
            int c4 = (f & 15) * 4;
            size_t g = (rowbase + l) * E_ + e0 + c4;
            *reinterpret_cast<f32x4*>(&sd[l][c4])  = *reinterpret_cast<const f32x4*>(&delta[g]);
            *reinterpret_cast<f32x4*>(&sx[l][c4])  = *reinterpret_cast<const f32x4*>(&xs[g]);
            *reinterpret_cast<f32x4*>(&ssk[l][c4]) = *reinterpret_cast<const f32x4*>(&skip[g]);
        }
        {
            int f = t & 127;
            int l = f >> 2;
            int c4 = (f & 3) * 4;
            size_t gb = (rowbase + l) * 16 + c4;
            if (t < 128)
                *reinterpret_cast<f32x4*>(&sB[l][c4]) = *reinterpret_cast<const f32x4*>(&Bm[gb]);
            else
                *reinterpret_cast<f32x4*>(&sC[l][c4]) = *reinterpret_cast<const f32x4*>(&Cm[gb]);
        }
        __syncthreads();
#pragma unroll 4
        for (int l = 0; l < CL_; ++l) {
            float d = sd[l][ci];
            float xv = sx[l][ci];
            f32x4 Bv = *reinterpret_cast<const f32x4*>(&sB[l][q * 4]);
            f32x4 Cv = *reinterpret_cast<const f32x4*>(&sC[l][q * 4]);
            f32x4 e4;
#pragma unroll
            for (int i = 0; i < 4; ++i) e4[i] = __expf(d * A4[i]);
            float dx = d * xv;
            h = e4 * h + dx * Bv;
            f32x4 yp = h * Cv;
            float y = (yp[0] + yp[1]) + (yp[2] + yp[3]);
            y += __shfl_xor(y, 1, 64);
            y += __shfl_xor(y, 2, 64);
            if (q == 0) {
                float g = silu_f(ssk[l][ci]);
                syg[l][ci] = f2bf((y + xv * wd) * g);
            }
        }
        __syncthreads();
        {
            int l = t >> 3;
            int col = (t & 7) * 8;
            *reinterpret_cast<uint4*>(&yg[(rowbase + l) * E_ + e0 + col]) =
                *reinterpret_cast<const uint4*>(&syg[l][col]);
        }
    }
}

extern "C" void kernel_launch(void* const* d_in, const int* in_sizes, int n_in,
                              void* d_out, int out_size, void* d_ws, size_t ws_size,
                              hipStream_t stream) {
    const float* resid  = (const float*)d_in[0];
    const float* norm_w = (const float*)d_in[1];
    const float* skip_w = (const float*)d_in[2];
    const float* in_w   = (const float*)d_in[3];
    const float* conv_w = (const float*)d_in[4];
    const float* conv_b = (const float*)d_in[5];
    const float* Wd1    = (const float*)d_in[6];
    const float* Wd2_w  = (const float*)d_in[7];
    const float* Wd2_b  = (const float*)d_in[8];
    const float* WB     = (const float*)d_in[9];
    const float* WC     = (const float*)d_in[10];
    const float* A_log  = (const float*)d_in[11];
    const float* W_D    = (const float*)d_in[12];
    const float* out_w  = (const float*)d_in[13];
    float* out = (float*)d_out;

    const int M = B_ * L_;                 // 8192
    char* p = (char*)d_ws;
    ushort* xn_bf   = (ushort*)p;  p += (size_t)M * D_ * 2;   // RMSNorm out (bf16)
    ushort* skw_bf  = (ushort*)p;  p += (size_t)E_ * D_ * 2;
    ushort* inw_bf  = (ushort*)p;  p += (size_t)E_ * D_ * 2;
    ushort* outw_bf = (ushort*)p;  p += (size_t)D_ * E_ * 2;
    ushort* yg_bf   = (ushort*)p;  p += (size_t)M * E_ * 2;
    float*  skipb   = (float*)p;   p += (size_t)M * E_ * 4;
    float*  xin     = (float*)p;   p += (size_t)M * E_ * 4;   // also delta (alias)
    float*  xs      = (float*)p;   p += (size_t)M * E_ * 4;
    float*  d1      = (float*)p;   p += (size_t)M * DD_ * 4;
    float*  Bm      = (float*)p;   p += (size_t)M * 16 * 4;
    float*  Cm      = (float*)p;   p += (size_t)M * 16 * 4;
    float*  delta   = xin;
    // scan scratch aliases xn_bf (dead after in/skip GEMMs): 8.6 MB < 16.8 MB
    float*  hloc    = (float*)xn_bf;                       // [B*S][E][16]
    float*  hin     = hloc + (size_t)B_ * S_SEG * E_ * 16; // [B*S][E][16]
    float*  sdsum   = hin  + (size_t)B_ * S_SEG * E_ * 16; // [B*S][E]

    dim3 blk(256);

    // weight casts (6M elems total)
    k_cast_bf<<<dim3((E_ * D_) / 1024), blk, 0, stream>>>(skip_w, skw_bf);
    k_cast_bf<<<dim3((E_ * D_) / 1024), blk, 0, stream>>>(in_w, inw_bf);
    k_cast_bf<<<dim3((D_ * E_) / 1024), blk, 0, stream>>>(out_w, outw_bf);
    // 1. RMSNorm -> bf16
    k_rmsnorm_bf<<<dim3(M), blk, 0, stream>>>(resid, norm_w, xn_bf);
    // 2. skip = xn @ skip_w^T   [M,E]  (bf16 MFMA)
    k_gemm_bf<0><<<dim3(E_ / 128, M / 128), blk, 0, stream>>>(xn_bf, skw_bf, nullptr, skipb, M, E_, D_);
    // 3. xin = xn @ in_w^T      [M,E]  (bf16 MFMA)
    k_gemm_bf<0><<<dim3(E_ / 128, M / 128), blk, 0, stream>>>(xn_bf, inw_bf, nullptr, xin, M, E_, D_);
    // 4. xs = silu(conv(xin)+b)
    k_conv_silu<<<dim3((M * E_) / 256), blk, 0, stream>>>(xin, conv_w, conv_b, xs);
    // 5. d1 = xs @ Wd1^T        [M,64]
    k_gemm_tn<0><<<dim3(DD_ / 64, M / 64), blk, 0, stream>>>(xs, Wd1, nullptr, d1, M, DD_, E_);
    // 6. delta = softplus(d1 @ Wd2^T + b) [M,E]
    k_gemm_tn<1><<<dim3(E_ / 64, M / 64), blk, 0, stream>>>(d1, Wd2_w, Wd2_b, delta, M, E_, DD_);
    // 7. Bm, Cm
    k_bc<<<dim3(M / 8), blk, 0, stream>>>(xs, WB, WC, Bm, Cm);
    // 8. segmented scan: p1 local scans, p2 chain, p3 full scan + gate -> bf16
    k_scan_p1<<<dim3(B_ * 32 * S_SEG), blk, 0, stream>>>(xs, delta, Bm, A_log, hloc, sdsum);
    k_scan_p2<<<dim3((B_ * E_ * 4) / 256), blk, 0, stream>>>(hloc, sdsum, A_log, hin);
    k_scan_p3<<<dim3(B_ * 32 * S_SEG), blk, 0, stream>>>(xs, delta, Bm, Cm, A_log, W_D,
                                                          skipb, hin, yg_bf);
    // 9. out = resid + yg @ out_w^T  (bf16 MFMA)
    k_gemm_bf<2><<<dim3(D_ / 128, M / 128), blk, 0, stream>>>(yg_bf, outw_bf, resid, out, M, D_, E_);
}

// Round 5
// 664.910 us; speedup vs baseline: 5.0101x; 1.5127x over previous
//
#include <hip/hip_runtime.h>
#include <hip/hip_bf16.h>
#include <math.h>

#define B_ 4
#define L_ 2048
#define D_ 1024
#define E_ 2048
#define N_ 16
#define DD_ 64
#define DCONV_ 4

#define S_SEG 8
#define SEGLEN_ (L_ / S_SEG)   // 256
#define CL_ 32

typedef __attribute__((ext_vector_type(8))) short bf16x8;
typedef __attribute__((ext_vector_type(4))) float f32x4;

static __device__ __forceinline__ float silu_f(float x) {
    return x / (1.f + __expf(-x));
}

static __device__ __forceinline__ ushort f2bf(float f) {
    __hip_bfloat16 h = __float2bfloat16(f);
    return *reinterpret_cast<ushort*>(&h);
}

// ---------------- RMSNorm: resid [B*L, D] -> xn (bf16) ----------------
__global__ __launch_bounds__(256) void k_rmsnorm_bf(const float* __restrict__ resid,
                                                    const float* __restrict__ nw,
                                                    ushort* __restrict__ out) {
    int row = blockIdx.x;
    const float* r = resid + (size_t)row * D_;
    int t = threadIdx.x;
    float4 v = *reinterpret_cast<const float4*>(&r[t * 4]);
    float ss = v.x * v.x + v.y * v.y + v.z * v.z + v.w * v.w;
#pragma unroll
    for (int o = 32; o >= 1; o >>= 1) ss += __shfl_xor(ss, o, 64);
    __shared__ float red[4];
    if ((t & 63) == 0) red[t >> 6] = ss;
    __syncthreads();
    float tot = red[0] + red[1] + red[2] + red[3];
    float rs = rsqrtf(tot * (1.f / (float)D_) + 1e-5f);
    float4 w4 = *reinterpret_cast<const float4*>(&nw[t * 4]);
    ushort4 o4;
    o4.x = f2bf(v.x * rs * w4.x);
    o4.y = f2bf(v.y * rs * w4.y);
    o4.z = f2bf(v.z * rs * w4.z);
    o4.w = f2bf(v.w * rs * w4.w);
    *reinterpret_cast<ushort4*>(&out[(size_t)row * D_ + t * 4]) = o4;
}

// ---------------- f32 -> bf16 cast (for weights) ----------------
__global__ __launch_bounds__(256) void k_cast_bf(const float* __restrict__ in,
                                                 ushort* __restrict__ out) {
    int i = blockIdx.x * 256 + threadIdx.x;  // float4 index
    float4 v = *reinterpret_cast<const float4*>(&in[i * 4]);
    ushort4 o;
    o.x = f2bf(v.x); o.y = f2bf(v.y); o.z = f2bf(v.z); o.w = f2bf(v.w);
    *reinterpret_cast<ushort4*>(&out[i * 4]) = o;
}

// ---------------- bf16 MFMA GEMM: C[M,N] = A[M,K] @ W[N,K]^T ----------------
// EPI: 0 = plain f32 store, 2 = += addsrc (residual) then f32 store
template <int EPI>
__global__ __launch_bounds__(256) void k_gemm_bf(const ushort* __restrict__ A,
                                                 const ushort* __restrict__ W,
                                                 const float* __restrict__ addsrc,
                                                 float* __restrict__ C,
                                                 int M, int N, int K) {
    constexpr int BM = 128, BN = 128, BK = 32, LDB = 40;  // 40 bf16 = 80B row stride
    __shared__ __align__(16) ushort As[BM * LDB];
    __shared__ __align__(16) ushort Ws[BN * LDB];
    int t = threadIdx.x;
    int m0 = blockIdx.y * BM, n0 = blockIdx.x * BN;
    int wave = t >> 6, lane = t & 63;
    int wr = wave >> 1, wc = wave & 1;     // wave quadrant (64x64)
    int lr = lane & 15, lg = lane >> 4;    // frag row/col, k-group

    f32x4 acc[4][4] = {};

    for (int k0 = 0; k0 < K; k0 += BK) {
#pragma unroll
        for (int p = 0; p < 2; ++p) {
            int f = t + p * 256;           // 16B chunk id, 0..511
            int row = f >> 2;              // 0..127
            int cg = (f & 3) * 8;          // bf16 col 0,8,16,24
            *reinterpret_cast<uint4*>(&As[row * LDB + cg]) =
                *reinterpret_cast<const uint4*>(&A[(size_t)(m0 + row) * K + k0 + cg]);
            *reinterpret_cast<uint4*>(&Ws[row * LDB + cg]) =
                *reinterpret_cast<const uint4*>(&W[(size_t)(n0 + row) * K + k0 + cg]);
        }
        __syncthreads();
        bf16x8 af[4], bfr[4];
#pragma unroll
        for (int i = 0; i < 4; ++i) {
            af[i]  = *reinterpret_cast<const bf16x8*>(&As[(wr * 64 + i * 16 + lr) * LDB + lg * 8]);
            bfr[i] = *reinterpret_cast<const bf16x8*>(&Ws[(wc * 64 + i * 16 + lr) * LDB + lg * 8]);
        }
#pragma unroll
        for (int i = 0; i < 4; ++i)
#pragma unroll
            for (int j = 0; j < 4; ++j)
                acc[i][j] = __builtin_amdgcn_mfma_f32_16x16x32_bf16(af[i], bfr[j], acc[i][j], 0, 0, 0);
        __syncthreads();
    }

#pragma unroll
    for (int i = 0; i < 4; ++i) {
        int mrow = m0 + wr * 64 + i * 16 + lg * 4;
#pragma unroll
        for (int j = 0; j < 4; ++j) {
            int ncol = n0 + wc * 64 + j * 16 + lr;
#pragma unroll
            for (int q = 0; q < 4; ++q) {
                float v = acc[i][j][q];
                size_t idx = (size_t)(mrow + q) * N + ncol;
                if (EPI == 2) v += addsrc[idx];
                C[idx] = v;
            }
        }
    }
}

// ---------------- fused skinny projections: [Bm|Cm|d1] = xs_bf @ wbc_bf^T ----------------
// wbc rows: 0-15 = WB, 16-31 = WC, 32-95 = Wd1.  M=8192, N=96, K=2048.
// BM=32 -> 256 blocks; 4 waves: rows (w>>1)*16, cols (w&1)*48 (3 frag-cols).
__global__ __launch_bounds__(256) void k_proj(const ushort* __restrict__ A,
                                              const ushort* __restrict__ Wc,
                                              float* __restrict__ Bm,
                                              float* __restrict__ Cm,
                                              float* __restrict__ d1) {
    constexpr int BK = 32, LDB = 40;
    __shared__ __align__(16) ushort As[32 * LDB];
    __shared__ __align__(16) ushort Ws[96 * LDB];
    int t = threadIdx.x;
    int m0 = blockIdx.x * 32;
    int wave = t >> 6, lane = t & 63;
    int rowbase = (wave >> 1) * 16;
    int colbase = (wave & 1) * 48;
    int lr = lane & 15, lg = lane >> 4;

    f32x4 acc[3] = {};

    for (int k0 = 0; k0 < E_; k0 += BK) {
        if (t < 128) {                      // A: 32 rows x 4 chunks
            int row = t >> 2;
            int cg = (t & 3) * 8;
            *reinterpret_cast<uint4*>(&As[row * LDB + cg]) =
                *reinterpret_cast<const uint4*>(&A[(size_t)(m0 + row) * E_ + k0 + cg]);
        }
        {                                   // W: 96 rows x 4 = 384 chunks
            int f = t;
            int row = f >> 2, cg = (f & 3) * 8;
            *reinterpret_cast<uint4*>(&Ws[row * LDB + cg]) =
                *reinterpret_cast<const uint4*>(&Wc[(size_t)row * E_ + k0 + cg]);
            if (t < 128) {
                int f2 = t + 256;
                int row2 = f2 >> 2, cg2 = (f2 & 3) * 8;
                *reinterpret_cast<uint4*>(&Ws[row2 * LDB + cg2]) =
                    *reinterpret_cast<const uint4*>(&Wc[(size_t)row2 * E_ + k0 + cg2]);
            }
        }
        __syncthreads();
        bf16x8 af = *reinterpret_cast<const bf16x8*>(&As[(rowbase + lr) * LDB + lg * 8]);
#pragma unroll
        for (int j = 0; j < 3; ++j) {
            bf16x8 bf = *reinterpret_cast<const bf16x8*>(&Ws[(colbase + j * 16 + lr) * LDB + lg * 8]);
            acc[j] = __builtin_amdgcn_mfma_f32_16x16x32_bf16(af, bf, acc[j], 0, 0, 0);
        }
        __syncthreads();
    }

#pragma unroll
    for (int j = 0; j < 3; ++j) {
        int ncol = colbase + j * 16 + lr;
#pragma unroll
        for (int q = 0; q < 4; ++q) {
            int m = m0 + rowbase + lg * 4 + q;
            float v = acc[j][q];
            if (ncol < 16)      Bm[(size_t)m * 16 + ncol] = v;
            else if (ncol < 32) Cm[(size_t)m * 16 + (ncol - 16)] = v;
            else                d1[(size_t)m * 64 + (ncol - 32)] = v;
        }
    }
}

// ---------------- f32 GEMM (Wd2 projection) ----------------
// EPI: 1 = softplus(acc + bias[n])
template <int EPI>
__global__ __launch_bounds__(256) void k_gemm_tn(const float* __restrict__ A,
                                                 const float* __restrict__ W,
                                                 const float* __restrict__ bias,
                                                 float* __restrict__ C,
                                                 int M, int N, int K) {
    constexpr int BM = 64, BN = 64, BK = 32;
    constexpr int LDP = 68;
    __shared__ __align__(16) float As[BK][LDP];
    __shared__ __align__(16) float Ws[BK][LDP];
    int tid = threadIdx.x;
    int tx = tid & 15;
    int ty = tid >> 4;
    int m0 = blockIdx.y * BM;
    int n0 = blockIdx.x * BN;

    float acc[4][4];
#pragma unroll
    for (int i = 0; i < 4; ++i)
#pragma unroll
        for (int j = 0; j < 4; ++j) acc[i][j] = 0.f;

    for (int k0 = 0; k0 < K; k0 += BK) {
#pragma unroll
        for (int p = 0; p < 2; ++p) {
            int idx = tid + p * 256;
            int row = idx >> 3;
            int col4 = (idx & 7) * 4;
            float4 av = *reinterpret_cast<const float4*>(&A[(size_t)(m0 + row) * K + k0 + col4]);
            As[col4 + 0][row] = av.x;
            As[col4 + 1][row] = av.y;
            As[col4 + 2][row] = av.z;
            As[col4 + 3][row] = av.w;
            float4 wv = *reinterpret_cast<const float4*>(&W[(size_t)(n0 + row) * K + k0 + col4]);
            Ws[col4 + 0][row] = wv.x;
            Ws[col4 + 1][row] = wv.y;
            Ws[col4 + 2][row] = wv.z;
            Ws[col4 + 3][row] = wv.w;
        }
        __syncthreads();
#pragma unroll
        for (int kk = 0; kk < BK; ++kk) {
            float4 a4 = *reinterpret_cast<const float4*>(&As[kk][ty * 4]);
            float4 b4 = *reinterpret_cast<const float4*>(&Ws[kk][tx * 4]);
            float a[4] = {a4.x, a4.y, a4.z, a4.w};
            float b[4] = {b4.x, b4.y, b4.z, b4.w};
#pragma unroll
            for (int i = 0; i < 4; ++i)
#pragma unroll
                for (int j = 0; j < 4; ++j) acc[i][j] = fmaf(a[i], b[j], acc[i][j]);
        }
        __syncthreads();
    }

#pragma unroll
    for (int i = 0; i < 4; ++i) {
        int m = m0 + ty * 4 + i;
        int nbase = n0 + tx * 4;
        float4 o4;
        float vals[4];
#pragma unroll
        for (int j = 0; j < 4; ++j) {
            float v = acc[i][j];
            if (EPI == 1) {
                float z = v + bias[nbase + j];
                vals[j] = (z > 20.f) ? z : log1pf(expf(z));
            } else {
                vals[j] = v;
            }
        }
        o4.x = vals[0]; o4.y = vals[1]; o4.z = vals[2]; o4.w = vals[3];
        *reinterpret_cast<float4*>(&C[(size_t)m * N + nbase]) = o4;
    }
}

// ---------------- depthwise causal conv1d + bias + silu (f32 + bf16 out) ----------------
__global__ __launch_bounds__(256) void k_conv_silu(const float* __restrict__ x,
                                                   const float* __restrict__ w,
                                                   const float* __restrict__ bias,
                                                   float* __restrict__ out,
                                                   ushort* __restrict__ out_bf) {
    int idx = blockIdx.x * 256 + threadIdx.x;
    int e = idx & (E_ - 1);
    int l = (idx / E_) & (L_ - 1);
    float4 wv = *reinterpret_cast<const float4*>(&w[e * 4]);
    float acc = bias[e];
    acc = fmaf(wv.w, x[idx], acc);
    if (l >= 1) acc = fmaf(wv.z, x[idx - E_], acc);
    if (l >= 2) acc = fmaf(wv.y, x[idx - 2 * E_], acc);
    if (l >= 3) acc = fmaf(wv.x, x[idx - 3 * E_], acc);
    float s = silu_f(acc);
    out[idx] = s;
    out_bf[idx] = f2bf(s);
}

// ================= segmented selective scan =================
__global__ __launch_bounds__(256) void k_scan_p1(const float* __restrict__ xs,
                                                 const float* __restrict__ delta,
                                                 const float* __restrict__ Bm,
                                                 const float* __restrict__ A_log,
                                                 float* __restrict__ hloc,
                                                 float* __restrict__ sdsum) {
    __shared__ __align__(16) float sd[CL_][64];
    __shared__ __align__(16) float sx[CL_][64];
    __shared__ __align__(16) float sB[CL_][16];
    int t = threadIdx.x;
    int q = t & 3, ci = t >> 2;
    int bid = blockIdx.x;
    int s = bid & 7;
    int eblk = (bid >> 3) & 31;
    int b = bid >> 8;
    int e0 = eblk * 64;
    int e = e0 + ci;

    f32x4 A4;
    {
        f32x4 al = *reinterpret_cast<const f32x4*>(&A_log[e * 16 + q * 4]);
#pragma unroll
        for (int i = 0; i < 4; ++i) A4[i] = -__expf(al[i]);
    }
    f32x4 h = {0.f, 0.f, 0.f, 0.f};
    float sdl = 0.f;

    for (int l0 = 0; l0 < SEGLEN_; l0 += CL_) {
        size_t rowbase = (size_t)b * L_ + s * SEGLEN_ + l0;
#pragma unroll
        for (int p = 0; p < 2; ++p) {
            int f = t + p * 256;
            int l = f >> 4;
            int c4 = (f & 15) * 4;
            size_t g = (rowbase + l) * E_ + e0 + c4;
            *reinterpret_cast<f32x4*>(&sd[l][c4]) = *reinterpret_cast<const f32x4*>(&delta[g]);
            *reinterpret_cast<f32x4*>(&sx[l][c4]) = *reinterpret_cast<const f32x4*>(&xs[g]);
        }
        if (t < 128) {
            int l = t >> 2;
            int c4 = (t & 3) * 4;
            *reinterpret_cast<f32x4*>(&sB[l][c4]) =
                *reinterpret_cast<const f32x4*>(&Bm[(rowbase + l) * 16 + c4]);
        }
        __syncthreads();
#pragma unroll 4
        for (int l = 0; l < CL_; ++l) {
            float d = sd[l][ci];
            float xv = sx[l][ci];
            f32x4 Bv = *reinterpret_cast<const f32x4*>(&sB[l][q * 4]);
            f32x4 e4;
#pragma unroll
            for (int i = 0; i < 4; ++i) e4[i] = __expf(d * A4[i]);
            float dx = d * xv;
            h = e4 * h + dx * Bv;
            sdl += d;
        }
        __syncthreads();
    }
    size_t idx = (size_t)(b * S_SEG + s) * E_ + e;
    *reinterpret_cast<f32x4*>(&hloc[idx * 16 + q * 4]) = h;
    if (q == 0) sdsum[idx] = sdl;
}

__global__ __launch_bounds__(256) void k_scan_p2(const float* __restrict__ hloc,
                                                 const float* __restrict__ sdsum,
                                                 const float* __restrict__ A_log,
                                                 float* __restrict__ hin) {
    int t = blockIdx.x * 256 + threadIdx.x;   // B*E*4 threads
    int q = t & 3;
    int e = (t >> 2) & (E_ - 1);
    int b = t >> 13;
    f32x4 A4;
    {
        f32x4 al = *reinterpret_cast<const f32x4*>(&A_log[e * 16 + q * 4]);
#pragma unroll
        for (int i = 0; i < 4; ++i) A4[i] = -__expf(al[i]);
    }
    f32x4 acc = {0.f, 0.f, 0.f, 0.f};
#pragma unroll
    for (int s = 0; s < S_SEG; ++s) {
        size_t idx = (size_t)(b * S_SEG + s) * E_ + e;
        *reinterpret_cast<f32x4*>(&hin[idx * 16 + q * 4]) = acc;
        float sd = sdsum[idx];
        f32x4 hl = *reinterpret_cast<const f32x4*>(&hloc[idx * 16 + q * 4]);
        f32x4 p;
#pragma unroll
        for (int i = 0; i < 4; ++i) p[i] = __expf(A4[i] * sd);
        acc = hl + p * acc;
    }
}

__global__ __launch_bounds__(256) void k_scan_p3(const float* __restrict__ xs,
                                                 const float* __restrict__ delta,
                                                 const float* __restrict__ Bm,
                                                 const float* __restrict__ Cm,
                                                 const float* __restrict__ A_log,
                                                 const float* __restrict__ W_D,
                                                 const float* __restrict__ skip,
                                                 const float* __restrict__ hin,
                                                 ushort* __restrict__ yg) {
    __shared__ __align__(16) float sd[CL_][64];
    __shared__ __align__(16) float sx[CL_][64];
    __shared__ __align__(16) float ssk[CL_][64];
    __shared__ __align__(16) float sB[CL_][16];
    __shared__ __align__(16) float sC[CL_][16];
    __shared__ __align__(16) ushort syg[CL_][64];
    int t = threadIdx.x;
    int q = t & 3, ci = t >> 2;
    int bid = blockIdx.x;
    int s = bid & 7;
    int eblk = (bid >> 3) & 31;
    int b = bid >> 8;
    int e0 = eblk * 64;
    int e = e0 + ci;

    f32x4 A4;
    {
        f32x4 al = *reinterpret_cast<const f32x4*>(&A_log[e * 16 + q * 4]);
#pragma unroll
        for (int i = 0; i < 4; ++i) A4[i] = -__expf(al[i]);
    }
    size_t cidx = (size_t)(b * S_SEG + s) * E_ + e;
    f32x4 h = *reinterpret_cast<const f32x4*>(&hin[cidx * 16 + q * 4]);
    float wd = W_D[e];

    for (int l0 = 0; l0 < SEGLEN_; l0 += CL_) {
        size_t rowbase = (size_t)b * L_ + s * SEGLEN_ + l0;
#pragma unroll
        for (int p = 0; p < 2; ++p) {
            int f = t + p * 256;
            int l = f >> 4;
            int c4 = (f & 15) * 4;
            size_t g = (rowbase + l) * E_ + e0 + c4;
            *reinterpret_cast<f32x4*>(&sd[l][c4])  = *reinterpret_cast<const f32x4*>(&delta[g]);
            *reinterpret_cast<f32x4*>(&sx[l][c4])  = *reinterpret_cast<const f32x4*>(&xs[g]);
            *reinterpret_cast<f32x4*>(&ssk[l][c4]) = *reinterpret_cast<const f32x4*>(&skip[g]);
        }
        {
            int f = t & 127;
            int l = f >> 2;
            int c4 = (f & 3) * 4;
            size_t gb = (rowbase + l) * 16 + c4;
            if (t < 128)
                *reinterpret_cast<f32x4*>(&sB[l][c4]) = *reinterpret_cast<const f32x4*>(&Bm[gb]);
            else
                *reinterpret_cast<f32x4*>(&sC[l][c4]) = *reinterpret_cast<const f32x4*>(&Cm[gb]);
        }
        __syncthreads();
#pragma unroll 4
        for (int l = 0; l < CL_; ++l) {
            float d = sd[l][ci];
            float xv = sx[l][ci];
            f32x4 Bv = *reinterpret_cast<const f32x4*>(&sB[l][q * 4]);
            f32x4 Cv = *reinterpret_cast<const f32x4*>(&sC[l][q * 4]);
            f32x4 e4;
#pragma unroll
            for (int i = 0; i < 4; ++i) e4[i] = __expf(d * A4[i]);
            float dx = d * xv;
            h = e4 * h + dx * Bv;
            f32x4 yp = h * Cv;
            float y = (yp[0] + yp[1]) + (yp[2] + yp[3]);
            y += __shfl_xor(y, 1, 64);
            y += __shfl_xor(y, 2, 64);
            if (q == 0) {
                float g = silu_f(ssk[l][ci]);
                syg[l][ci] = f2bf((y + xv * wd) * g);
            }
        }
        __syncthreads();
        {
            int l = t >> 3;
            int col = (t & 7) * 8;
            *reinterpret_cast<uint4*>(&yg[(rowbase + l) * E_ + e0 + col]) =
                *reinterpret_cast<const uint4*>(&syg[l][col]);
        }
    }
}

extern "C" void kernel_launch(void* const* d_in, const int* in_sizes, int n_in,
                              void* d_out, int out_size, void* d_ws, size_t ws_size,
                              hipStream_t stream) {
    const float* resid  = (const float*)d_in[0];
    const float* norm_w = (const float*)d_in[1];
    const float* skip_w = (const float*)d_in[2];
    const float* in_w   = (const float*)d_in[3];
    const float* conv_w = (const float*)d_in[4];
    const float* conv_b = (const float*)d_in[5];
    const float* Wd1    = (const float*)d_in[6];
    const float* Wd2_w  = (const float*)d_in[7];
    const float* Wd2_b  = (const float*)d_in[8];
    const float* WB     = (const float*)d_in[9];
    const float* WC     = (const float*)d_in[10];
    const float* A_log  = (const float*)d_in[11];
    const float* W_D    = (const float*)d_in[12];
    const float* out_w  = (const float*)d_in[13];
    float* out = (float*)d_out;

    const int M = B_ * L_;                 // 8192
    char* p = (char*)d_ws;
    ushort* xn_bf   = (ushort*)p;  p += (size_t)M * D_ * 2;   // RMSNorm out (bf16)
    ushort* skw_bf  = (ushort*)p;  p += (size_t)E_ * D_ * 2;
    ushort* inw_bf  = (ushort*)p;  p += (size_t)E_ * D_ * 2;
    ushort* outw_bf = (ushort*)p;  p += (size_t)D_ * E_ * 2;
    ushort* yg_bf   = (ushort*)p;  p += (size_t)M * E_ * 2;   // also xs_bf (alias, disjoint)
    float*  skipb   = (float*)p;   p += (size_t)M * E_ * 4;
    float*  xin     = (float*)p;   p += (size_t)M * E_ * 4;   // also delta (alias)
    float*  xs      = (float*)p;   p += (size_t)M * E_ * 4;
    float*  d1      = (float*)p;   p += (size_t)M * DD_ * 4;
    float*  Bm      = (float*)p;   p += (size_t)M * 16 * 4;
    float*  Cm      = (float*)p;   p += (size_t)M * 16 * 4;
    ushort* wbc_bf  = (ushort*)p;  p += (size_t)96 * E_ * 2;  // [WB;WC;Wd1] bf16
    float*  delta   = xin;
    ushort* xs_bf   = yg_bf;       // alias: xs_bf dead before p3 writes yg
    // scan scratch aliases xn_bf (dead after in/skip GEMMs): 8.6 MB < 16.8 MB
    float*  hloc    = (float*)xn_bf;                       // [B*S][E][16]
    float*  hin     = hloc + (size_t)B_ * S_SEG * E_ * 16; // [B*S][E][16]
    float*  sdsum   = hin  + (size_t)B_ * S_SEG * E_ * 16; // [B*S][E]

    dim3 blk(256);

    // weight casts
    k_cast_bf<<<dim3((E_ * D_) / 1024), blk, 0, stream>>>(skip_w, skw_bf);
    k_cast_bf<<<dim3((E_ * D_) / 1024), blk, 0, stream>>>(in_w, inw_bf);
    k_cast_bf<<<dim3((D_ * E_) / 1024), blk, 0, stream>>>(out_w, outw_bf);
    k_cast_bf<<<dim3((N_ * E_) / 1024), blk, 0, stream>>>(WB, wbc_bf);
    k_cast_bf<<<dim3((N_ * E_) / 1024), blk, 0, stream>>>(WC, wbc_bf + (size_t)16 * E_);
    k_cast_bf<<<dim3((DD_ * E_) / 1024), blk, 0, stream>>>(Wd1, wbc_bf + (size_t)32 * E_);
    // 1. RMSNorm -> bf16
    k_rmsnorm_bf<<<dim3(M), blk, 0, stream>>>(resid, norm_w, xn_bf);
    // 2. skip = xn @ skip_w^T   [M,E]  (bf16 MFMA)
    k_gemm_bf<0><<<dim3(E_ / 128, M / 128), blk, 0, stream>>>(xn_bf, skw_bf, nullptr, skipb, M, E_, D_);
    // 3. xin = xn @ in_w^T      [M,E]  (bf16 MFMA)
    k_gemm_bf<0><<<dim3(E_ / 128, M / 128), blk, 0, stream>>>(xn_bf, inw_bf, nullptr, xin, M, E_, D_);
    // 4. xs = silu(conv(xin)+b), also bf16 copy
    k_conv_silu<<<dim3((M * E_) / 256), blk, 0, stream>>>(xin, conv_w, conv_b, xs, xs_bf);
    // 5+7. fused skinny projections: Bm, Cm, d1 = xs_bf @ [WB;WC;Wd1]^T (bf16 MFMA)
    k_proj<<<dim3(M / 32), blk, 0, stream>>>(xs_bf, wbc_bf, Bm, Cm, d1);
    // 6. delta = softplus(d1 @ Wd2^T + b) [M,E]
    k_gemm_tn<1><<<dim3(E_ / 64, M / 64), blk, 0, stream>>>(d1, Wd2_w, Wd2_b, delta, M, E_, DD_);
    // 8. segmented scan: p1 local scans, p2 chain, p3 full scan + gate -> bf16
    k_scan_p1<<<dim3(B_ * 32 * S_SEG), blk, 0, stream>>>(xs, delta, Bm, A_log, hloc, sdsum);
    k_scan_p2<<<dim3((B_ * E_ * 4) / 256), blk, 0, stream>>>(hloc, sdsum, A_log, hin);
    k_scan_p3<<<dim3(B_ * 32 * S_SEG), blk, 0, stream>>>(xs, delta, Bm, Cm, A_log, W_D,
                                                          skipb, hin, yg_bf);
    // 9. out = resid + yg @ out_w^T  (bf16 MFMA)
    k_gemm_bf<2><<<dim3(D_ / 128, M / 128), blk, 0, stream>>>(yg_bf, outw_bf, resid, out, M, D_, E_);
}